// Round 7
// baseline (374.311 us; speedup 1.0000x reference)
//
#include <hip/hip_runtime.h>
#include <cmath>

#ifndef __has_builtin
#define __has_builtin(x) 0
#endif

#define B_DIM 4096
#define K_DIM 2048
#define N_DIM 2048

#define BM 128
#define BN 64
#define BK 64    // i8: 64 B per row = 4 x 16B chunks; tile buffer 8+4+4 = 16 KB

typedef __attribute__((ext_vector_type(4))) float f32x4;
typedef __attribute__((ext_vector_type(4))) int i32x4;
typedef __attribute__((ext_vector_type(16))) signed char i8x16;

// ---------- helpers ----------

__device__ __forceinline__ signed char f2i8(float f) {
    int t = __float2int_rn(f);               // round-half-even, matches rintf/ste_round
    t = t < -127 ? -127 : (t > 127 ? 127 : t);
    return (signed char)t;
}

__device__ __forceinline__ void gl2lds16(const void* g, void* l) {
#if __has_builtin(__builtin_amdgcn_global_load_lds)
    __builtin_amdgcn_global_load_lds((__attribute__((address_space(1))) void*)g,
                                     (__attribute__((address_space(3))) void*)l,
                                     16, 0, 0);
#else
    *(uint4*)l = *(const uint4*)g;
#endif
}

#define VMWAIT_(n) asm volatile("s_waitcnt vmcnt(" #n ")" ::: "memory")
#define VMWAIT(n)  VMWAIT_(n)
#define LGKM0      asm volatile("s_waitcnt lgkmcnt(0)" ::: "memory")
#define FENCE      asm volatile("" ::: "memory")
#define SBARRIER   do { FENCE; __builtin_amdgcn_s_barrier(); FENCE; } while (0)
// LDS-only barrier: orders DS ops across waves WITHOUT draining vmcnt --
// global loads/stores keep flying across it (unlike __syncthreads).
#define LDSBARRIER do { LGKM0; SBARRIER; } while (0)

// ---------- prep: fp32 -> i8 casts (single launch) ----------
// X entries are exactly 0.0/1.0; ste_round(W) is integral. i8/i32 GEMM is
// exact (numSyn <= 2048*127 << 2^31), bit-identical to the f32 einsum.

__global__ void cast_all_kernel(const float* __restrict__ X,
                                const float* __restrict__ Wa,
                                const float* __restrict__ Ws,
                                signed char* __restrict__ Xb,
                                signed char* __restrict__ Wab,
                                signed char* __restrict__ Wsb) {
    const int bid = blockIdx.x;
    if (bid < 2048) {
        size_t i = ((size_t)bid * 256 + threadIdx.x) * 16;
        i8x16 o;
#pragma unroll
        for (int j = 0; j < 16; j += 4) {
            f32x4 a = *(const f32x4*)(X + i + j);
            o[j]     = f2i8(a[0]);
            o[j + 1] = f2i8(a[1]);
            o[j + 2] = f2i8(a[2]);
            o[j + 3] = f2i8(a[3]);
        }
        *(i8x16*)(Xb + i) = o;
    } else {
        size_t i = ((size_t)(bid - 2048) * 256 + threadIdx.x) * 16;
        i8x16 oa, os;
#pragma unroll
        for (int j = 0; j < 16; j += 4) {
            f32x4 a = *(const f32x4*)(Wa + i + j);
            f32x4 s = *(const f32x4*)(Ws + i + j);
            oa[j]     = f2i8(a[0]); oa[j + 1] = f2i8(a[1]);
            oa[j + 2] = f2i8(a[2]); oa[j + 3] = f2i8(a[3]);
            os[j]     = f2i8(s[0]); os[j + 1] = f2i8(s[1]);
            os[j + 2] = f2i8(s[2]); os[j + 3] = f2i8(s[3]);
        }
        *(i8x16*)(Wab + i) = oa;
        *(i8x16*)(Wsb + i) = os;
    }
}

// ---------- fused dual-GEMM + DPI neuron update ----------
//
// STREAMING-BLOCK variant of the verified R4/R6 pipeline: 128x64 tile,
// 1024 blocks, 3 x 16 KB buffers (48 KB LDS), __launch_bounds__(256,3) ->
// 3 resident blocks/CU, 4 assigned per CU.  Blocks desynchronize, so one
// block's epilogue (HBM+VALU) overlaps another's GEMM (MFMA) -- attacking
// the measured phase-alignment loss (GEMM 62 us vs ~20 floor; epilogue at
// its 45 us HBM floor).  K-loop macro-structure is UNCHANGED from R4/R6:
// ds_reads FIRST, stage SECOND, counted vmcnt (now 4 loads/thread/tile ->
// WAITN=4), no setprio, vmcnt(0) only at the peeled last tile.
//
// Hazard ledger (same as R4/R6, loads renumbered):
//  * stage(t+2) overwrites buf[(t-1)%3]; its readers retired before tile
//    t's top barrier (DS in-order) -> safe.
//  * reads(buf t): own 4 DMA loads retired by vmcnt(4) (FIFO oldest),
//    other waves' by the barrier.
//  * epilogue scatter aliases buf0 -> trailing SBARRIER after the loop.
//  * prologue stages FENCE-separated (per-thread tile-FIFO issue order).
//
// Bank swizzle: rows are still 64 B, so the proven slot16 read swizzle and
// source pre-swizzle carry over verbatim (measured 0 conflicts).

#define RS 68        // LDS float row stride for epilogue (64 + 4 pad)
#define BUFSZ 16384  // one pipeline buffer: A 8 KB + Wa 4 KB + Ws 4 KB

__device__ __forceinline__ void stage_tile(int tt, int bufIdx, int tid, int m0, int n0,
                                           unsigned char* smem,
                                           const signed char* __restrict__ Xb,
                                           const signed char* __restrict__ Wab,
                                           const signed char* __restrict__ Wsb) {
    unsigned char* bb = smem + bufIdx * BUFSZ;
    const int k0s = tt * BK;
    // A: 128 rows x 64 B = 512 chunks; 2 per thread
#pragma unroll
    for (int j = 0; j < 2; j++) {
        const int c   = j * 256 + tid;
        const int row = c >> 2;                    // 4 chunks per row
        const int js  = (c & 3) ^ ((row >> 1) & 3);
        gl2lds16(Xb + (size_t)(m0 + row) * K_DIM + k0s + js * 16, bb + c * 16);
    }
    // Wa / Ws: 64 rows x 4 chunks = 256 chunks each; 1+1 per thread
    {
        const int row = tid >> 2;
        const int js  = (tid & 3) ^ ((row >> 1) & 3);
        const size_t go = (size_t)(n0 + row) * K_DIM + k0s + js * 16;
        gl2lds16(Wab + go, bb + 8192  + tid * 16);
        gl2lds16(Wsb + go, bb + 12288 + tid * 16);
    }
}

// one pipeline step: wait(oldest tile landed) -> barrier -> ds_reads ->
// issue stage(t+2) -> pin -> 16 MFMA.  WAITN / DOSTG are compile-time.
#define TILE_STEP(t_, rb_, sb_, WAITN, DOSTG)                                 \
{                                                                             \
  VMWAIT(WAITN); SBARRIER;                                                    \
  const unsigned char* bb = smem + (rb_) * BUFSZ;                             \
  const signed char* sA  = (const signed char*)bb;                            \
  const signed char* sWa = (const signed char*)(bb + 8192);                   \
  const signed char* sWs = (const signed char*)(bb + 12288);                  \
  i32x4 af[4], ba[2], bs[2];                                                  \
  _Pragma("unroll") for (int mi = 0; mi < 4; mi++)                            \
      af[mi] = *(const i32x4*)(sA + (wm + mi * 16 + frow) * 64 + slot16);     \
  _Pragma("unroll") for (int ni = 0; ni < 2; ni++) {                          \
      const int o = (wn + ni * 16 + frow) * 64 + slot16;                      \
      ba[ni] = *(const i32x4*)(sWa + o);                                      \
      bs[ni] = *(const i32x4*)(sWs + o);                                      \
  }                                                                           \
  if (DOSTG) stage_tile((t_) + 2, (sb_), tid, m0, n0, smem, Xb, Wab, Wsb);    \
  __builtin_amdgcn_sched_barrier(0);                                          \
  _Pragma("unroll") for (int mi = 0; mi < 4; mi++)                            \
  _Pragma("unroll") for (int ni = 0; ni < 2; ni++) {                          \
      accA[mi][ni] = __builtin_amdgcn_mfma_i32_16x16x64_i8(af[mi], ba[ni], accA[mi][ni], 0, 0, 0); \
      accS[mi][ni] = __builtin_amdgcn_mfma_i32_16x16x64_i8(af[mi], bs[ni], accS[mi][ni], 0, 0, 0); \
  }                                                                           \
}

__global__ __launch_bounds__(256, 3)
void dpi_fused_kernel(const signed char* __restrict__ Xb,
                      const signed char* __restrict__ Wab,
                      const signed char* __restrict__ Wsb,
                      const float* __restrict__ gImem,
                      const float* __restrict__ gIampa,
                      const float* __restrict__ gIshunt,
                      const float* __restrict__ gRefr,
                      const float* __restrict__ pIdc,
                      const float* __restrict__ pIwa,
                      const float* __restrict__ pIws,
                      const float* __restrict__ pAlpha,
                      const float* __restrict__ pBeta,
                      float* __restrict__ out,
                      float i0pow, float kexp, float tau_mem, float inv_tau_syn)
{
    __shared__ __align__(16) unsigned char smem[49152];   // 3 x 16 KB pipeline bufs
    float* na_buf = (float*)smem;                         // epilogue reuse: 32*RS*4 = 8704 B
    float* ns_buf = (float*)(smem + 8704);                // 8704 B

    const int tid  = threadIdx.x;
    const int lane = tid & 63;
    const int wave = tid >> 6;

    // bijective XCD swizzle: 1024 blocks on a 32(mb) x 32(nb) grid; each XCD
    // gets an 8(mb) x 16(nb) region for L2 locality.
    const int lin = blockIdx.x;                 // 0..1023
    const int xcd = lin & 7;
    const int loc = lin >> 3;                   // 0..127
    const int mb  = (xcd & 3) * 8 + (loc & 7);  // 0..31
    const int nb  = (xcd >> 2) * 16 + (loc >> 3);// 0..31
    const int m0  = mb * BM;
    const int n0  = nb * BN;

    const int wm = (wave & 1) * 64;   // M-half of the 128-row tile
    const int wn = (wave >> 1) * 32;  // N-half of the 64-col tile

    i32x4 accA[4][2], accS[4][2];
#pragma unroll
    for (int i = 0; i < 4; i++)
#pragma unroll
        for (int j = 0; j < 2; j++) { accA[i][j] = (i32x4)0; accS[i][j] = (i32x4)0; }

    const int frow   = lane & 15;                       // m (or n) within a 16-frag
    const int kq     = lane >> 4;                       // k sub-chunk 0..3
    const int slot16 = (kq ^ ((frow >> 1) & 3)) * 16;   // swizzled 16B slot (rows 64B,
                                                        // identical math to R4/R6)

    // prologue: tiles 0,1 in flight (8 loads/thread, tile-FIFO order)
    stage_tile(0, 0, tid, m0, n0, smem, Xb, Wab, Wsb); FENCE;
    stage_tile(1, 1, tid, m0, n0, smem, Xb, Wab, Wsb); FENCE;

    // main loop: 30 tiles staging t+2, then 2 peeled drain tiles.
    // buffer rotation: read t%3, stage into (t+2)%3.
    for (int tb = 0; tb < 30; tb += 3) {
        TILE_STEP(tb + 0, 0, 2, 4, 1);
        TILE_STEP(tb + 1, 1, 0, 4, 1);
        TILE_STEP(tb + 2, 2, 1, 4, 1);
    }
    TILE_STEP(30, 0, 2, 4, 0);
    TILE_STEP(31, 1, 0, 0, 0);

    // all DMA retired (vmcnt(0) at tile 31); reads of buf0/buf1 retired
    // before each wave reaches this barrier -> epilogue may overwrite them.
    SBARRIER;

    // ---- epilogue: transpose through LDS, then contiguous float4 I/O ----
    // LDS-only barriers: the 5-plane stores and state loads fly ACROSS the
    // step barriers instead of being drained by __syncthreads' vmcnt(0).
    const float idc   = *pIdc;
    const float iwa   = *pIwa;
    const float iws   = *pIws;
    const float alpha = *pAlpha;
    const float beta  = *pBeta;

    const size_t plane = (size_t)B_DIM * N_DIM;
    float* __restrict__ oSpike = out;
    float* __restrict__ oImem  = out + plane;
    float* __restrict__ oIampa = out + 2 * plane;
    float* __restrict__ oIsh   = out + 3 * plane;
    float* __restrict__ oRefr  = out + 4 * plane;

    const int rowgroup = wm >> 6;          // 0 or 1
    const int quad4    = (lane >> 4) << 2; // 0,4,8,12
    const int cseg     = (tid & 15) * 4;   // float4 column (64 cols = 16 float4)
    const int rrow     = tid >> 4;         // 0..15 -> base row of this thread

#pragma unroll
    for (int s = 0; s < 4; s++) {          // s == mi: 32 rows of the tile per step
        // scatter fragments into LDS (C/D layout: col=lane&15, row=quad*4+r)
#pragma unroll
        for (int ni = 0; ni < 2; ni++) {
            const int lcol = wn + ni * 16 + (lane & 15);
#pragma unroll
            for (int r = 0; r < 4; r++) {
                const int lrow = rowgroup * 16 + quad4 + r;
                na_buf[lrow * RS + lcol] = (float)accA[s][ni][r];
                ns_buf[lrow * RS + lcol] = (float)accS[s][ni][r];
            }
        }
        LDSBARRIER;   // scatter visible; VMEM (stores of step s-1) keeps flying

        // contiguous compute + store: each thread owns 2 rows x 1 float4
#pragma unroll
        for (int q = 0; q < 2; q++) {
            const int lrow = rrow + q * 16;
            const int grow = m0 + (lrow >> 4) * 64 + s * 16 + (lrow & 15);
            const size_t idx = (size_t)grow * N_DIM + n0 + cseg;

            const f32x4 na4 = *(const f32x4*)(na_buf + lrow * RS + cseg);
            const f32x4 ns4 = *(const f32x4*)(ns_buf + lrow * RS + cseg);
            const f32x4 im4 = *(const f32x4*)(gImem   + idx);
            const f32x4 ia4 = *(const f32x4*)(gIampa  + idx);
            const f32x4 is4 = *(const f32x4*)(gIshunt + idx);
            const f32x4 rf4 = *(const f32x4*)(gRefr   + idx);

            f32x4 sp_o, im_o, ia_o, is_o, rf_o;
#pragma unroll
            for (int e = 0; e < 4; e++) {
                const float na  = na4[e];
                const float ns  = ns4[e];
                const float im  = im4[e];
                const float ia  = ia4[e];
                const float ish = is4[e];
                const float rf  = rf4[e];

                const float dIampa  = -ia * inv_tau_syn;
                const float ia2     = ia + iwa * na;        // IGAIN_AMPA/ITAU_AMPA = 1
                const float dIshunt = -ish * inv_tau_syn;   // TAU_SHUNT == TAU_AMPA
                const float ish2    = ish + iws * ns;

                float Iin = idc + ia2 + 5e-13f - ish2;      // Inmda = I0
                Iin = (rf <= 0.0f) ? Iin : 0.0f;
                Iin = fmaxf(Iin, 5e-13f);

                // 1+exp(-1e-12*(im-1e-12)): |arg| < 1e-21 -> exp == 1.0f exactly
                // in fp32, denominator == 2.0f. powf via v_log/v_exp.
                const float ifb = i0pow *
                    __builtin_amdgcn_exp2f(kexp * __builtin_amdgcn_logf(im)) * 0.5f;
                const float fimem = ifb * 1e12f * (im + 1e-12f);
                const float dImem = (alpha * ((Iin - 1e-12f) - 5e-13f) - beta * im + fimem)
                                    / (tau_mem * (1.0f + 1e-12f / im));
                float im2 = fmaxf(im + dImem * 0.001f, 5e-13f);

                float ia3 = fmaxf(ia2 + dIampa * 0.001f, 5e-13f);
                ia3       = fmaxf(ia3 + dIshunt * 0.001f, 5e-13f);  // faithful to ref bug

                const float spike = (im2 - 1e-12f > 0.0f) ? 1.0f : 0.0f;
                im2 = (spike > 0.0f) ? 5e-13f : im2;
                float rf2 = fmaxf(rf - 0.001f, 0.0f);
                rf2 = (spike > 0.0f) ? 0.0f : rf2;          // REFP = 0

                sp_o[e] = spike; im_o[e] = im2; ia_o[e] = ia3;
                is_o[e] = ish2;  rf_o[e] = rf2;
            }

            *(f32x4*)(oSpike + idx) = sp_o;
            *(f32x4*)(oImem  + idx) = im_o;
            *(f32x4*)(oIampa + idx) = ia_o;
            *(f32x4*)(oIsh   + idx) = is_o;
            *(f32x4*)(oRefr  + idx) = rf_o;
        }

        LDSBARRIER;   // this step's LDS reads retired; stores keep flying
    }
}

// ---------- launch ----------

extern "C" void kernel_launch(void* const* d_in, const int* in_sizes, int n_in,
                              void* d_out, int out_size, void* d_ws, size_t ws_size,
                              hipStream_t stream) {
    (void)in_sizes; (void)n_in; (void)out_size; (void)ws_size;

    const float* X       = (const float*)d_in[0];
    const float* W_ampa  = (const float*)d_in[1];
    const float* W_shunt = (const float*)d_in[2];
    const float* Imem    = (const float*)d_in[3];
    const float* Iampa   = (const float*)d_in[4];
    const float* Ishunt  = (const float*)d_in[5];
    const float* Refr    = (const float*)d_in[6];
    const float* pIdc    = (const float*)d_in[7];
    const float* pIwa    = (const float*)d_in[8];
    const float* pIws    = (const float*)d_in[9];
    const float* pAlpha  = (const float*)d_in[10];
    const float* pBeta   = (const float*)d_in[11];

    signed char* Xb  = (signed char*)d_ws;                 // 8 MiB
    signed char* Wab = Xb  + (size_t)B_DIM * K_DIM;        // 4 MiB
    signed char* Wsb = Wab + (size_t)N_DIM * K_DIM;        // 4 MiB

    const float i0pow       = (float)std::pow(5e-13, 1.0 / 1.705);   // I0^(1/(k+1))
    const float kexp        = (float)(0.705 / 1.705);                // k/(k+1)
    const float tau_mem     = (float)(0.025 / 0.705 * 3.0);
    const float inv_tau_syn = (float)(1.0 / (0.025 / 0.705 * 2.0));

    cast_all_kernel<<<dim3(3072), dim3(256), 0, stream>>>(
        X, W_ampa, W_shunt, Xb, Wab, Wsb);

    dpi_fused_kernel<<<dim3(1024), dim3(256), 0, stream>>>(
        Xb, Wab, Wsb, Imem, Iampa, Ishunt, Refr,
        pIdc, pIwa, pIws, pAlpha, pBeta,
        (float*)d_out, i0pow, kexp, tau_mem, inv_tau_syn);
}

// Round 8
// 352.951 us; speedup vs baseline: 1.0605x; 1.0605x over previous
//
#include <hip/hip_runtime.h>
#include <cmath>

#ifndef __has_builtin
#define __has_builtin(x) 0
#endif

#define B_DIM 4096
#define K_DIM 2048
#define N_DIM 2048

#define BM 256
#define BN 128
#define BK 64    // i8: 64 B per row = 4 x 16B chunks; tile buffer 16+8+8 = 32 KB

typedef __attribute__((ext_vector_type(4))) float f32x4;
typedef __attribute__((ext_vector_type(4))) int i32x4;
typedef __attribute__((ext_vector_type(16))) signed char i8x16;

// ---------- helpers ----------

__device__ __forceinline__ signed char f2i8(float f) {
    int t = __float2int_rn(f);               // round-half-even, matches rintf/ste_round
    t = t < -127 ? -127 : (t > 127 ? 127 : t);
    return (signed char)t;
}

__device__ __forceinline__ void gl2lds16(const void* g, void* l) {
#if __has_builtin(__builtin_amdgcn_global_load_lds)
    __builtin_amdgcn_global_load_lds((__attribute__((address_space(1))) void*)g,
                                     (__attribute__((address_space(3))) void*)l,
                                     16, 0, 0);
#else
    *(uint4*)l = *(const uint4*)g;
#endif
}

#define VMWAIT_(n) asm volatile("s_waitcnt vmcnt(" #n ")" ::: "memory")
#define VMWAIT(n)  VMWAIT_(n)
#define FENCE      asm volatile("" ::: "memory")
#define SBARRIER   do { FENCE; __builtin_amdgcn_s_barrier(); FENCE; } while (0)

// ---------- prep: fp32 -> i8 casts (single launch) ----------
// X entries are exactly 0.0/1.0; ste_round(W) is integral. i8/i32 GEMM is
// exact (numSyn <= 2048*127 << 2^31), bit-identical to the f32 einsum.

__global__ void cast_all_kernel(const float* __restrict__ X,
                                const float* __restrict__ Wa,
                                const float* __restrict__ Ws,
                                signed char* __restrict__ Xb,
                                signed char* __restrict__ Wab,
                                signed char* __restrict__ Wsb) {
    const int bid = blockIdx.x;
    if (bid < 2048) {
        size_t i = ((size_t)bid * 256 + threadIdx.x) * 16;
        i8x16 o;
#pragma unroll
        for (int j = 0; j < 16; j += 4) {
            f32x4 a = *(const f32x4*)(X + i + j);
            o[j]     = f2i8(a[0]);
            o[j + 1] = f2i8(a[1]);
            o[j + 2] = f2i8(a[2]);
            o[j + 3] = f2i8(a[3]);
        }
        *(i8x16*)(Xb + i) = o;
    } else {
        size_t i = ((size_t)(bid - 2048) * 256 + threadIdx.x) * 16;
        i8x16 oa, os;
#pragma unroll
        for (int j = 0; j < 16; j += 4) {
            f32x4 a = *(const f32x4*)(Wa + i + j);
            f32x4 s = *(const f32x4*)(Ws + i + j);
            oa[j]     = f2i8(a[0]); oa[j + 1] = f2i8(a[1]);
            oa[j + 2] = f2i8(a[2]); oa[j + 3] = f2i8(a[3]);
            os[j]     = f2i8(s[0]); os[j + 1] = f2i8(s[1]);
            os[j + 2] = f2i8(s[2]); os[j + 3] = f2i8(s[3]);
        }
        *(i8x16*)(Wab + i) = oa;
        *(i8x16*)(Wsb + i) = os;
    }
}

// ---------- fused dual-GEMM + DPI neuron update ----------
//
// BIG-TILE variant of the verified R4/R6 pipeline: 256x128 tile, 512 threads
// (8 waves as 4M x 2N, each wave the SAME 64x64 / 12-ds_read / 32-MFMA inner
// step as R6), grid 256 = 1 block/CU (8 waves/CU -- same wave occupancy as
// R6's 2x4).  vs R6: tile-steps per chip halve (8192 vs 16384), MFMA per
// step doubles (fixed-cost amortization: the lever R7 proved by its inverse),
// staged bytes 384 -> 256 MB.  K-loop macro-structure UNCHANGED: ds_reads
// FIRST, stage SECOND, counted vmcnt (4 loads/thread/tile -> WAITN=4), no
// setprio, vmcnt(0) only at the peeled last tile.
//
// Hazard ledger (same as R4/R6, loads renumbered):
//  * stage(t+2) overwrites buf[(t-1)%3]; its readers were consumed by tile
//    t-1's MFMAs before each wave entered tile t's top barrier; DS ops
//    retire in order -> overwrite safe.
//  * reads(buf t): own 4 DMA loads retired by vmcnt(4) (FIFO oldest),
//    other waves' by the barrier.
//  * epilogue scatter aliases buf0/buf1 -> trailing SBARRIER after the loop.
//  * prologue stages FENCE-separated (per-thread tile-FIFO issue order).
//
// Bank swizzle: rows are 64 B as before; read slot16 = (kq ^ ((frow>>1)&3))
// and matching global source pre-swizzle carry over verbatim (row = 16a +
// frow keeps (row>>1)&3 == (frow>>1)&3).  Measured 0 conflicts in R4/R6.
//
// LDS: 3 x 32 KB = 96 KB; __launch_bounds__(512,2) -> 2 waves/SIMD min,
// VGPR cap 256 (acc = 128 regs + temps ~ 200 total).

#define RS 132       // LDS float row stride for epilogue (128 + 4 pad)
#define BUFSZ 32768  // one pipeline buffer: A 16 KB + Wa 8 KB + Ws 8 KB

__device__ __forceinline__ void stage_tile(int tt, int bufIdx, int tid, int m0, int n0,
                                           unsigned char* smem,
                                           const signed char* __restrict__ Xb,
                                           const signed char* __restrict__ Wab,
                                           const signed char* __restrict__ Wsb) {
    unsigned char* bb = smem + bufIdx * BUFSZ;
    const int k0s = tt * BK;
    // A: 256 rows x 64 B = 1024 chunks; 2 per thread (512 threads)
#pragma unroll
    for (int j = 0; j < 2; j++) {
        const int c   = j * 512 + tid;
        const int row = c >> 2;                    // 4 chunks per row
        const int js  = (c & 3) ^ ((row >> 1) & 3);
        gl2lds16(Xb + (size_t)(m0 + row) * K_DIM + k0s + js * 16, bb + c * 16);
    }
    // Wa / Ws: 128 rows x 4 chunks = 512 chunks each; 1+1 per thread
    {
        const int row = tid >> 2;
        const int js  = (tid & 3) ^ ((row >> 1) & 3);
        const size_t go = (size_t)(n0 + row) * K_DIM + k0s + js * 16;
        gl2lds16(Wab + go, bb + 16384 + tid * 16);
        gl2lds16(Wsb + go, bb + 24576 + tid * 16);
    }
}

// one pipeline step: wait(oldest tile landed) -> barrier -> ds_reads ->
// issue stage(t+2) -> pin -> 32 MFMA.  WAITN / DOSTG are compile-time.
#define TILE_STEP(t_, rb_, sb_, WAITN, DOSTG)                                 \
{                                                                             \
  VMWAIT(WAITN); SBARRIER;                                                    \
  const unsigned char* bb = smem + (rb_) * BUFSZ;                             \
  const signed char* sA  = (const signed char*)bb;                            \
  const signed char* sWa = (const signed char*)(bb + 16384);                  \
  const signed char* sWs = (const signed char*)(bb + 24576);                  \
  i32x4 af[4], ba[4], bs[4];                                                  \
  _Pragma("unroll") for (int mi = 0; mi < 4; mi++)                            \
      af[mi] = *(const i32x4*)(sA + (wm + mi * 16 + frow) * 64 + slot16);     \
  _Pragma("unroll") for (int ni = 0; ni < 4; ni++) {                          \
      const int o = (wn + ni * 16 + frow) * 64 + slot16;                      \
      ba[ni] = *(const i32x4*)(sWa + o);                                      \
      bs[ni] = *(const i32x4*)(sWs + o);                                      \
  }                                                                           \
  if (DOSTG) stage_tile((t_) + 2, (sb_), tid, m0, n0, smem, Xb, Wab, Wsb);    \
  __builtin_amdgcn_sched_barrier(0);                                          \
  _Pragma("unroll") for (int mi = 0; mi < 4; mi++)                            \
  _Pragma("unroll") for (int ni = 0; ni < 4; ni++) {                          \
      accA[mi][ni] = __builtin_amdgcn_mfma_i32_16x16x64_i8(af[mi], ba[ni], accA[mi][ni], 0, 0, 0); \
      accS[mi][ni] = __builtin_amdgcn_mfma_i32_16x16x64_i8(af[mi], bs[ni], accS[mi][ni], 0, 0, 0); \
  }                                                                           \
}

__global__ __launch_bounds__(512, 2)
void dpi_fused_kernel(const signed char* __restrict__ Xb,
                      const signed char* __restrict__ Wab,
                      const signed char* __restrict__ Wsb,
                      const float* __restrict__ gImem,
                      const float* __restrict__ gIampa,
                      const float* __restrict__ gIshunt,
                      const float* __restrict__ gRefr,
                      const float* __restrict__ pIdc,
                      const float* __restrict__ pIwa,
                      const float* __restrict__ pIws,
                      const float* __restrict__ pAlpha,
                      const float* __restrict__ pBeta,
                      float* __restrict__ out,
                      float i0pow, float kexp, float tau_mem, float inv_tau_syn)
{
    __shared__ __align__(16) unsigned char smem[98304];   // 3 x 32 KB pipeline bufs
    float* na_buf = (float*)smem;                         // epilogue: 64*RS*4 = 33792 B
    float* ns_buf = (float*)(smem + 33792);               // 33792 B (total 67.5 KB)

    const int tid  = threadIdx.x;
    const int lane = tid & 63;
    const int wave = tid >> 6;        // 0..7

    // bijective XCD swizzle: 256 blocks on a 16(mb) x 16(nb) grid; each XCD
    // gets an 8x4 region for L2 locality (verified bijection, R1 pattern).
    const int lin = blockIdx.x;       // 0..255
    const int xcd = lin & 7;
    const int loc = lin >> 3;         // 0..31
    const int mb  = (xcd & 1) * 8 + (loc >> 2);   // 0..15
    const int nb  = (xcd >> 1) * 4 + (loc & 3);   // 0..15
    const int m0  = mb * BM;
    const int n0  = nb * BN;

    const int wm = (wave >> 1) * 64;  // 0,64,128,192: wave's 64-row band
    const int wn = (wave & 1) * 64;   // 0,64: wave's 64-col band

    i32x4 accA[4][4], accS[4][4];
#pragma unroll
    for (int i = 0; i < 4; i++)
#pragma unroll
        for (int j = 0; j < 4; j++) { accA[i][j] = (i32x4)0; accS[i][j] = (i32x4)0; }

    const int frow   = lane & 15;                       // m (or n) within a 16-frag
    const int kq     = lane >> 4;                       // k sub-chunk 0..3
    const int slot16 = (kq ^ ((frow >> 1) & 3)) * 16;   // swizzled 16B slot

    // prologue: tiles 0,1 in flight (8 loads/thread, tile-FIFO order)
    stage_tile(0, 0, tid, m0, n0, smem, Xb, Wab, Wsb); FENCE;
    stage_tile(1, 1, tid, m0, n0, smem, Xb, Wab, Wsb); FENCE;

    // main loop: 30 tiles staging t+2, then 2 peeled drain tiles.
    // buffer rotation: read t%3, stage into (t+2)%3.
    for (int tb = 0; tb < 30; tb += 3) {
        TILE_STEP(tb + 0, 0, 2, 4, 1);
        TILE_STEP(tb + 1, 1, 0, 4, 1);
        TILE_STEP(tb + 2, 2, 1, 4, 1);
    }
    TILE_STEP(30, 0, 2, 4, 0);
    TILE_STEP(31, 1, 0, 0, 0);

    // all DMA retired (vmcnt(0) at tile 31); all buf reads retired before
    // each wave reaches this barrier -> epilogue may overwrite buf0/buf1.
    SBARRIER;

    // ---- epilogue: transpose through LDS, then contiguous float4 I/O ----
    // 4 steps of 64 contiguous output rows (m0 + s*64 ..).  Step s's rows
    // live in waves {2s, 2s+1} (wm == s*64); those waves scatter, then all
    // 512 threads compute + store with row-contiguous float4 (512 B runs).
    const float idc   = *pIdc;
    const float iwa   = *pIwa;
    const float iws   = *pIws;
    const float alpha = *pAlpha;
    const float beta  = *pBeta;

    const size_t plane = (size_t)B_DIM * N_DIM;
    float* __restrict__ oSpike = out;
    float* __restrict__ oImem  = out + plane;
    float* __restrict__ oIampa = out + 2 * plane;
    float* __restrict__ oIsh   = out + 3 * plane;
    float* __restrict__ oRefr  = out + 4 * plane;

    const int quad4 = (lane >> 4) << 2;    // 0,4,8,12
    const int cseg  = (tid & 31) * 4;      // float4 column (128 cols = 32 f4)
    const int rgrp  = tid >> 5;            // 0..15 -> rows rgrp*4..+3

#pragma unroll
    for (int s = 0; s < 4; s++) {
        // scatter (C/D layout: col=lane&15, row=quad*4+r; dtype-independent)
        if ((wave >> 1) == s) {
#pragma unroll
            for (int mi = 0; mi < 4; mi++)
#pragma unroll
            for (int ni = 0; ni < 4; ni++) {
                const int lcol = wn + ni * 16 + (lane & 15);
#pragma unroll
                for (int r = 0; r < 4; r++) {
                    const int lrow = mi * 16 + quad4 + r;       // 0..63
                    na_buf[lrow * RS + lcol] = (float)accA[mi][ni][r];
                    ns_buf[lrow * RS + lcol] = (float)accS[mi][ni][r];
                }
            }
        }
        __syncthreads();

        // contiguous compute + store: each thread owns 4 rows x 1 float4
#pragma unroll
        for (int q = 0; q < 4; q++) {
            const int lrow = rgrp * 4 + q;                      // 0..63
            const int grow = m0 + s * 64 + lrow;
            const size_t idx = (size_t)grow * N_DIM + n0 + cseg;

            const f32x4 na4 = *(const f32x4*)(na_buf + lrow * RS + cseg);
            const f32x4 ns4 = *(const f32x4*)(ns_buf + lrow * RS + cseg);
            const f32x4 im4 = *(const f32x4*)(gImem   + idx);
            const f32x4 ia4 = *(const f32x4*)(gIampa  + idx);
            const f32x4 is4 = *(const f32x4*)(gIshunt + idx);
            const f32x4 rf4 = *(const f32x4*)(gRefr   + idx);

            f32x4 sp_o, im_o, ia_o, is_o, rf_o;
#pragma unroll
            for (int e = 0; e < 4; e++) {
                const float na  = na4[e];
                const float ns  = ns4[e];
                const float im  = im4[e];
                const float ia  = ia4[e];
                const float ish = is4[e];
                const float rf  = rf4[e];

                const float dIampa  = -ia * inv_tau_syn;
                const float ia2     = ia + iwa * na;        // IGAIN_AMPA/ITAU_AMPA = 1
                const float dIshunt = -ish * inv_tau_syn;   // TAU_SHUNT == TAU_AMPA
                const float ish2    = ish + iws * ns;

                float Iin = idc + ia2 + 5e-13f - ish2;      // Inmda = I0
                Iin = (rf <= 0.0f) ? Iin : 0.0f;
                Iin = fmaxf(Iin, 5e-13f);

                // 1+exp(-1e-12*(im-1e-12)): |arg| < 1e-21 -> exp == 1.0f exactly
                // in fp32, denominator == 2.0f. powf via v_log/v_exp.
                const float ifb = i0pow *
                    __builtin_amdgcn_exp2f(kexp * __builtin_amdgcn_logf(im)) * 0.5f;
                const float fimem = ifb * 1e12f * (im + 1e-12f);
                const float dImem = (alpha * ((Iin - 1e-12f) - 5e-13f) - beta * im + fimem)
                                    / (tau_mem * (1.0f + 1e-12f / im));
                float im2 = fmaxf(im + dImem * 0.001f, 5e-13f);

                float ia3 = fmaxf(ia2 + dIampa * 0.001f, 5e-13f);
                ia3       = fmaxf(ia3 + dIshunt * 0.001f, 5e-13f);  // faithful to ref bug

                const float spike = (im2 - 1e-12f > 0.0f) ? 1.0f : 0.0f;
                im2 = (spike > 0.0f) ? 5e-13f : im2;
                float rf2 = fmaxf(rf - 0.001f, 0.0f);
                rf2 = (spike > 0.0f) ? 0.0f : rf2;          // REFP = 0

                sp_o[e] = spike; im_o[e] = im2; ia_o[e] = ia3;
                is_o[e] = ish2;  rf_o[e] = rf2;
            }

            *(f32x4*)(oSpike + idx) = sp_o;
            *(f32x4*)(oImem  + idx) = im_o;
            *(f32x4*)(oIampa + idx) = ia_o;
            *(f32x4*)(oIsh   + idx) = is_o;
            *(f32x4*)(oRefr  + idx) = rf_o;
        }
        __syncthreads();
    }
}

// ---------- launch ----------

extern "C" void kernel_launch(void* const* d_in, const int* in_sizes, int n_in,
                              void* d_out, int out_size, void* d_ws, size_t ws_size,
                              hipStream_t stream) {
    (void)in_sizes; (void)n_in; (void)out_size; (void)ws_size;

    const float* X       = (const float*)d_in[0];
    const float* W_ampa  = (const float*)d_in[1];
    const float* W_shunt = (const float*)d_in[2];
    const float* Imem    = (const float*)d_in[3];
    const float* Iampa   = (const float*)d_in[4];
    const float* Ishunt  = (const float*)d_in[5];
    const float* Refr    = (const float*)d_in[6];
    const float* pIdc    = (const float*)d_in[7];
    const float* pIwa    = (const float*)d_in[8];
    const float* pIws    = (const float*)d_in[9];
    const float* pAlpha  = (const float*)d_in[10];
    const float* pBeta   = (const float*)d_in[11];

    signed char* Xb  = (signed char*)d_ws;                 // 8 MiB
    signed char* Wab = Xb  + (size_t)B_DIM * K_DIM;        // 4 MiB
    signed char* Wsb = Wab + (size_t)N_DIM * K_DIM;        // 4 MiB

    const float i0pow       = (float)std::pow(5e-13, 1.0 / 1.705);   // I0^(1/(k+1))
    const float kexp        = (float)(0.705 / 1.705);                // k/(k+1)
    const float tau_mem     = (float)(0.025 / 0.705 * 3.0);
    const float inv_tau_syn = (float)(1.0 / (0.025 / 0.705 * 2.0));

    cast_all_kernel<<<dim3(3072), dim3(256), 0, stream>>>(
        X, W_ampa, W_shunt, Xb, Wab, Wsb);

    dpi_fused_kernel<<<dim3(256), dim3(512), 0, stream>>>(
        Xb, Wab, Wsb, Imem, Iampa, Ishunt, Refr,
        pIdc, pIwa, pIws, pAlpha, pBeta,
        (float*)d_out, i0pow, kexp, tau_mem, inv_tau_syn);
}